// Round 14
// baseline (509.707 us; speedup 1.0000x reference)
//
#include <hip/hip_runtime.h>
#include <math.h>

#define N 8192
#define M 8192
#define C 96
#define OUT 20
#define LG 2048

#define NSPA 8      // y-slices pass A (64-wide n-tiles, 16 per block)
#define NSPB 8      // y-slices pass B (64-wide mid tiles)

typedef _Float16 h8 __attribute__((ext_vector_type(8)));
typedef float    f4 __attribute__((ext_vector_type(4)));

// async global->LDS, 16B per lane, no VGPR round-trip
__device__ __forceinline__ void gl_lds16(const h8* g, h8* l) {
    __builtin_amdgcn_global_load_lds(
        (const __attribute__((address_space(1))) unsigned int*)g,
        (__attribute__((address_space(3))) unsigned int*)l,
        16, 0, 0);
}

// tile-slot-major h8 index: rows grouped in 128-row tiles, slot-major inside
__device__ __forceinline__ size_t tsm24(int row, int slot) {
    return ((size_t)(row >> 7) * 24 + slot) * 128 + (row & 127);
}

// ---------------- workspace layout (bytes, all 256-aligned) ----------------
constexpr size_t OFF_DIFF  = 0;
constexpr size_t OFF_AL    = 256;
constexpr size_t OFF_NMF2  = OFF_AL    + (size_t)M*3*4;
constexpr size_t OFF_UPDF  = OFF_NMF2  + (size_t)N*4;
constexpr size_t OFF_GTC   = OFF_UPDF  + (size_t)M*4;
constexpr size_t OFF_SMI   = OFF_GTC   + (size_t)M*4;
constexpr size_t OFF_PERM  = OFF_SMI   + (size_t)M*4;
constexpr size_t OFF_AP    = OFF_PERM  + (size_t)M*4;            // M x 192 fp16 (tsm24)
constexpr size_t OFF_BQ    = OFF_AP    + (size_t)M*192*2;        // N x 192 fp16
constexpr size_t OFF_MFP   = OFF_BQ    + (size_t)N*192*2;        // N x 192 fp16
constexpr size_t OFF_MIDQ  = OFF_MFP   + (size_t)N*192*2;        // (M+128) x 192 fp16
constexpr size_t OFF_MIDN2 = OFF_MIDQ  + (size_t)(M+128)*192*2;
constexpr size_t OFF_MIDC  = OFF_MIDN2 + (size_t)(M+128)*4;
constexpr size_t OFF_CLS   = OFF_MIDC  + (size_t)(M+128)*3*4;
constexpr size_t OFF_PAV   = OFF_CLS   + (size_t)(M+128)*4;      // NSPA x M
constexpr size_t OFF_PAI   = OFF_PAV   + (size_t)NSPA*M*4;
constexpr size_t OFF_UWACC = OFF_PAI   + (size_t)NSPA*M*4;       // N x 20 (atomic)
constexpr size_t OFF_VALS  = OFF_UWACC + (size_t)N*OUT*4;
constexpr size_t OFF_POS   = OFF_VALS  + (size_t)LG*4;
constexpr size_t OFF_MAXV  = OFF_POS   + (size_t)N*4;
constexpr size_t OFF_AMAX  = OFF_MAXV  + (size_t)N*4;
constexpr size_t OFF_FLAGS = OFF_AMAX  + (size_t)N*4;
constexpr size_t OFF_CNT   = OFF_FLAGS + 256;
constexpr size_t OFF_META  = OFF_CNT   + 256;   // [0]=Mact [1]=n 64-tiles [2..21]=cursor

// ---------------------------------------------------------------- 4x4 inverse
__global__ void k_diff(const float* __restrict__ posses, float* __restrict__ diff) {
    if (threadIdx.x != 0 || blockIdx.x != 0) return;
    float a[4][8];
    for (int i = 0; i < 4; i++)
        for (int j = 0; j < 4; j++) {
            a[i][j]     = posses[16 + i*4 + j];
            a[i][4 + j] = (i == j) ? 1.f : 0.f;
        }
    for (int col = 0; col < 4; col++) {
        int piv = col; float mx = fabsf(a[col][col]);
        for (int r = col + 1; r < 4; r++) {
            float v = fabsf(a[r][col]);
            if (v > mx) { mx = v; piv = r; }
        }
        if (piv != col)
            for (int j = 0; j < 8; j++) { float t = a[col][j]; a[col][j] = a[piv][j]; a[piv][j] = t; }
        float inv = 1.0f / a[col][col];
        for (int j = 0; j < 8; j++) a[col][j] *= inv;
        for (int r = 0; r < 4; r++) {
            if (r == col) continue;
            float f = a[r][col];
            for (int j = 0; j < 8; j++) a[r][j] -= f * a[col][j];
        }
    }
    for (int i = 0; i < 4; i++)
        for (int j = 0; j < 4; j++) {
            float s = 0.f;
            for (int k = 0; k < 4; k++) s += a[i][4 + k] * posses[k*4 + j];
            diff[i*4 + j] = s;
        }
}

// ---------------------------------------------------------------- per-m prep (+ class hist)
__global__ void k_prep_m(const float* __restrict__ ssf, const float* __restrict__ scoords,
                         const float* __restrict__ gt, const int* __restrict__ ran_mask,
                         const float* __restrict__ diff,
                         float* __restrict__ al, _Float16* __restrict__ aP,
                         float* __restrict__ updf, int* __restrict__ gtcls,
                         int* __restrict__ cnt) {
    __shared__ int hcnt[OUT];
    const int tt = threadIdx.x;
    if (tt < OUT) hcnt[tt] = 0;
    __syncthreads();
    const int m = blockIdx.x * 128 + (tt >> 1);
    const int h = tt & 1;
    {
        const float4* r4 = (const float4*)(ssf + (size_t)m * C);
        float4 row[24]; float s = 0.f;
        #pragma unroll
        for (int c = 0; c < 24; c++) {
            float4 v = r4[c];
            row[c] = v;
            s += v.x*v.x + v.y*v.y + v.z*v.z + v.w*v.w;
        }
        float scale = 256.0f / sqrtf(s);
        h8* dst = (h8*)aP;
        #pragma unroll
        for (int qq = 0; qq < 6; qq++) {
            int q = h*6 + qq;
            float4 u = row[2*q], v = row[2*q+1];
            float xs[8] = {u.x,u.y,u.z,u.w,v.x,v.y,v.z,v.w};
            h8 hi, lo;
            #pragma unroll
            for (int e = 0; e < 8; e++) {
                float xv = xs[e] * scale;
                _Float16 hh = (_Float16)xv;
                hi[e] = hh;
                lo[e] = (_Float16)(xv - (float)hh);
            }
            dst[tsm24(m, q)]      = hi;
            dst[tsm24(m, 12 + q)] = lo;
        }
        if (h == 0) {
            float x = scoords[m*3], y = scoords[m*3+1], z = scoords[m*3+2];
            #pragma unroll
            for (int j = 0; j < 3; j++)
                al[m*3 + j] = diff[j*4+0]*x + diff[j*4+1]*y + diff[j*4+2]*z + diff[j*4+3];
            int best = 0; float bv = gt[(size_t)m*OUT];
            #pragma unroll
            for (int k = 1; k < OUT; k++) {
                float v = gt[(size_t)m*OUT + k];
                if (v > bv) { bv = v; best = k; }
            }
            gtcls[m] = best;
            bool upd = (best < 9 || m < LG || ran_mask[m] == 1);
            updf[m] = upd ? 1.f : 0.f;
            if (upd) atomicAdd(&hcnt[best], 1);
        }
    }
    __syncthreads();
    if (tt < OUT) atomicAdd(&cnt[tt], hcnt[tt]);
}

// ---------------------------------------------------------------- per-n prep (2 threads/row)
__global__ void k_prep_n(const float* __restrict__ mf, _Float16* __restrict__ bQ,
                         _Float16* __restrict__ mfP, float* __restrict__ nmf2) {
    const int tt = threadIdx.x;
    const int n = blockIdx.x * 128 + (tt >> 1);
    const int h = tt & 1;
    const float4* r4 = (const float4*)(mf + (size_t)n * C);
    float4 row[24]; float s = 0.f;
    #pragma unroll
    for (int c = 0; c < 24; c++) {
        float4 v = r4[c];
        row[c] = v;
        s += v.x*v.x + v.y*v.y + v.z*v.z + v.w*v.w;
    }
    if (h == 0) nmf2[n] = s;
    float scn = 256.0f / sqrtf(s);
    h8* dB = (h8*)bQ;
    h8* dF = (h8*)mfP;
    #pragma unroll
    for (int qq = 0; qq < 6; qq++) {
        int q = h*6 + qq;
        float4 u = row[2*q], v = row[2*q+1];
        float xs[8] = {u.x,u.y,u.z,u.w,v.x,v.y,v.z,v.w};
        h8 hiN, loN, hiF, loF;
        #pragma unroll
        for (int e = 0; e < 8; e++) {
            float xn = xs[e] * scn;
            _Float16 hn = (_Float16)xn;
            hiN[e] = hn; loN[e] = (_Float16)(xn - (float)hn);
            float xf = xs[e] * 256.0f;
            _Float16 hf = (_Float16)xf;
            hiF[e] = hf; loF[e] = (_Float16)(xf - (float)hf);
        }
        dB[tsm24(n, q)]    = hiN;
        dB[tsm24(n, 12+q)] = loN;
        dF[tsm24(n, q)]    = hiF;
        dF[tsm24(n, 12+q)] = loF;
    }
}

// ---------------------------------------------------------------- pass A: MFMA argmin
// 256 threads (4 waves 2x2), 74 KB LDS -> 2 blocks/CU. Resident 128m full-K;
// streams 16 x 64-wide n-tiles via global_load_lds. Wave tile 64m x 32n.
__global__ __launch_bounds__(256, 2) void k_argmin(
        const _Float16* __restrict__ aP, const _Float16* __restrict__ bQ,
        const float* __restrict__ al, const float* __restrict__ ori,
        float* __restrict__ pav, int* __restrict__ pai) {
    __shared__ h8 sA[24*128];          // 48 KB
    __shared__ h8 sB[24*64];           // 24 KB
    __shared__ float xv[2*128];
    __shared__ int   xi[2*128];
    const int t = threadIdx.x;
    const int wave = t >> 6, lane = t & 63;
    const int col = lane & 15, quad = lane >> 4;
    const int wm = wave >> 1, wn = wave & 1;
    const int m0 = blockIdx.x * 128;
    const int sp = blockIdx.y;

    {   // stage resident A async (flat: tile layout == LDS layout), 12 per thread
        const h8* gA = (const h8*)aP + (size_t)blockIdx.x * 24 * 128;
        #pragma unroll
        for (int q = 0; q < 12; q++) gl_lds16(gA + q*256 + t, sA + q*256 + t);
    }
    float mcx[16], mcy[16], mcz[16];
    #pragma unroll
    for (int e = 0; e < 16; e++) {
        int ml = wm*64 + (e>>2)*16 + quad*4 + (e&3);
        mcx[e] = al[(m0+ml)*3+0]; mcy[e] = al[(m0+ml)*3+1]; mcz[e] = al[(m0+ml)*3+2];
    }
    float best[16]; int bidx[16];
    #pragma unroll
    for (int e = 0; e < 16; e++) { best[e] = 3.4e38f; bidx[e] = 0; }

    const h8* gB = (const h8*)bQ;
    f4 acc[4][2];
    for (int u = 0; u < 16; u++) {
        const int tt = sp + u*NSPA;            // 64-wide n-tile index (0..127)
        const int n0t = tt * 64;
        __syncthreads();                       // prev compute done reading sB
        {
            const h8* g = gB + (size_t)(tt >> 1) * 24 * 128 + (tt & 1) * 64;
            #pragma unroll
            for (int qq = 0; qq < 6; qq++) {
                int idx = qq*256 + t;
                int slot = idx >> 6, row = idx & 63;
                gl_lds16(g + slot*128 + row, sB + slot*64 + row);
            }
        }
        __syncthreads();                       // drains vmcnt -> sA/sB visible
        #pragma unroll
        for (int i = 0; i < 4; i++)
            #pragma unroll
            for (int j = 0; j < 2; j++) acc[i][j] = (f4){0.f,0.f,0.f,0.f};

        #pragma unroll
        for (int ks = 0; ks < 3; ks++) {
            const int hs = ks*4 + quad;        // hi slot; lo slot = 12+hs
            h8 ah[4], alo[4], bh[2], blo[2];
            #pragma unroll
            for (int i = 0; i < 4; i++) {
                int ml = wm*64 + i*16 + col;
                ah[i]  = sA[hs*128 + ml];
                alo[i] = sA[(12+hs)*128 + ml];
            }
            #pragma unroll
            for (int j = 0; j < 2; j++) {
                int r = wn*32 + j*16 + col;
                bh[j]  = sB[hs*64 + r];
                blo[j] = sB[(12+hs)*64 + r];
            }
            #pragma unroll
            for (int i = 0; i < 4; i++)
                #pragma unroll
                for (int j = 0; j < 2; j++) {
                    acc[i][j] = __builtin_amdgcn_mfma_f32_16x16x32_f16(ah[i],  bh[j],  acc[i][j], 0, 0, 0);
                    acc[i][j] = __builtin_amdgcn_mfma_f32_16x16x32_f16(ah[i],  blo[j], acc[i][j], 0, 0, 0);
                    acc[i][j] = __builtin_amdgcn_mfma_f32_16x16x32_f16(alo[i], bh[j],  acc[i][j], 0, 0, 0);
                }
        }
        // epilogue: running per-lane argmin over this tile
        #pragma unroll
        for (int j = 0; j < 2; j++) {
            int n = n0t + wn*32 + j*16 + col;
            float ncx = ori[n*3+0], ncy = ori[n*3+1], ncz = ori[n*3+2];
            #pragma unroll
            for (int e = 0; e < 16; e++) {
                float dot = acc[e>>2][j][e&3] * (1.0f/65536.0f);
                float dx = mcx[e]-ncx, dy = mcy[e]-ncy, dz = mcz[e]-ncz;
                float d2 = dx*dx + dy*dy + dz*dz;
                float sim = 2.0f - dot - __expf(-2.0f*d2);
                if (sim < best[e]) { best[e] = sim; bidx[e] = n; }
            }
        }
    }
    // butterfly over 16 col-lanes, once per block
    #pragma unroll
    for (int e = 0; e < 16; e++) {
        float bv = best[e]; int bi = bidx[e];
        #pragma unroll
        for (int d = 1; d < 16; d <<= 1) {
            float ov = __shfl_xor(bv, d, 64);
            int   oi = __shfl_xor(bi, d, 64);
            if (ov < bv || (ov == bv && oi < bi)) { bv = ov; bi = oi; }
        }
        best[e] = bv; bidx[e] = bi;
    }
    if (col == 0) {
        #pragma unroll
        for (int e = 0; e < 16; e++) {
            int ml = wm*64 + (e>>2)*16 + quad*4 + (e&3);
            xv[wn*128 + ml] = best[e];
            xi[wn*128 + ml] = bidx[e];
        }
    }
    __syncthreads();
    if (t < 128) {   // single writer per (sp, m): merge the 2 wn halves
        float bv = xv[t]; int bi = xi[t];
        float v1 = xv[128 + t]; int i1 = xi[128 + t];
        if (v1 < bv || (v1 == bv && i1 < bi)) { bv = v1; bi = i1; }
        pav[(size_t)sp * M + m0 + t] = bv;
        pai[(size_t)sp * M + m0 + t] = bi;
    }
}

__global__ void k_argmin_reduce(const float* __restrict__ pav, const int* __restrict__ pai,
                                int* __restrict__ smi, float* __restrict__ out_smi) {
    int m = blockIdx.x * 256 + threadIdx.x;
    if (m >= M) return;
    float best = 3.4e38f; int bidx = 0;
    for (int sp = 0; sp < NSPA; sp++) {
        float v = pav[(size_t)sp * M + m];
        int   i = pai[(size_t)sp * M + m];
        if (v < best || (v == best && i < bidx)) { best = v; bidx = i; }
    }
    smi[m] = bidx;
    out_smi[m] = (float)bidx;
}

// ---------------------------------------------------------------- scan + permute (counting sort)
__global__ void k_scan(const int* __restrict__ cnt, int* __restrict__ meta) {
    if (threadIdx.x != 0 || blockIdx.x != 0) return;
    int run = 0;
    for (int k = 0; k < OUT; k++) { meta[2 + k] = run; run += cnt[k]; }
    meta[0] = run;
    meta[1] = (run + 63) / 64;        // 64-wide mid tiles
}

__global__ void k_permute(const int* __restrict__ gtcls, const float* __restrict__ updf,
                          int* __restrict__ meta, int* __restrict__ perm) {
    int m = blockIdx.x * 256 + threadIdx.x;
    if (m >= M) return;
    if (updf[m] == 0.f) return;
    int pos = atomicAdd(&meta[2 + gtcls[m]], 1);
    perm[pos] = m;
}

// gather sorted+compacted mid rows (straight 24-slot copy), pad to 64 boundary
__global__ void k_gather_sorted(const int* __restrict__ meta, const int* __restrict__ perm,
                                const int* __restrict__ smi, const int* __restrict__ gtcls,
                                const _Float16* __restrict__ mfP, const float* __restrict__ nmf2,
                                const float* __restrict__ ori,
                                _Float16* __restrict__ midQ, float* __restrict__ midn2,
                                float* __restrict__ midc, int* __restrict__ cls_s) {
    int rr = blockIdx.x * 256 + threadIdx.x;
    int mact = meta[0];
    int mpad = meta[1] * 64;
    const h8* src = (const h8*)mfP;
    h8* dst = (h8*)midQ;
    if (rr < mact) {
        int m = perm[rr];
        int s = smi[m];
        #pragma unroll
        for (int q = 0; q < 24; q++) dst[tsm24(rr, q)] = src[tsm24(s, q)];
        midn2[rr] = nmf2[s];
        midc[rr*3+0] = ori[s*3+0];
        midc[rr*3+1] = ori[s*3+1];
        midc[rr*3+2] = ori[s*3+2];
        cls_s[rr] = gtcls[m];
    } else if (rr < mpad) {
        h8 z = (h8)(_Float16)0.f;
        #pragma unroll
        for (int q = 0; q < 24; q++) dst[tsm24(rr, q)] = z;
        midn2[rr] = 1e9f;     // w = exp(-5.55e9) == 0 exactly
        midc[rr*3+0] = 0.f; midc[rr*3+1] = 0.f; midc[rr*3+2] = 0.f;
        cls_s[rr] = 0;
    }
}

// ---------------------------------------------------------------- pass B: MFMA class-binned sums
// 256 threads (4 waves 2x2), 72 KB LDS -> 2 blocks/CU. Resident 128n full-K;
// streams 64-wide sorted mid tiles; class sums -> global uwacc via atomics.
__global__ __launch_bounds__(256, 2) void k_uw(
        const _Float16* __restrict__ mfP, const _Float16* __restrict__ midQ,
        const float* __restrict__ nmf2, const float* __restrict__ ori,
        const float* __restrict__ midn2, const float* __restrict__ midc,
        const int* __restrict__ cls_s, const int* __restrict__ meta,
        float* __restrict__ uwacc) {
    __shared__ h8 sN[24*128];          // 48 KB resident n-rows
    __shared__ h8 sB[24*64];           // 24 KB streamed mid tile
    const int t = threadIdx.x;
    const int wave = t >> 6, lane = t & 63;
    const int col = lane & 15, quad = lane >> 4;
    const int wm = wave >> 1, wn = wave & 1;   // wm: n-side halves, wn: m'-side halves
    const int n0 = blockIdx.x * 128;
    const int sp = blockIdx.y;
    const int nmac = meta[1];

    {   // stage resident n-rows async
        const h8* gN = (const h8*)mfP + (size_t)blockIdx.x * 24 * 128;
        #pragma unroll
        for (int q = 0; q < 12; q++) gl_lds16(gN + q*256 + t, sN + q*256 + t);
    }
    float nn2[16], ncx[16], ncy[16], ncz[16];
    #pragma unroll
    for (int e = 0; e < 16; e++) {
        int nl = wm*64 + (e>>2)*16 + quad*4 + (e&3);
        int n = n0 + nl;
        nn2[e] = nmf2[n];
        ncx[e] = ori[n*3+0]; ncy[e] = ori[n*3+1]; ncz[e] = ori[n*3+2];
    }

    const h8* gB = (const h8*)midQ;
    f4 acc[4][2];
    for (int mt = sp; mt < nmac; mt += NSPB) {
        const int mb = mt * 64;
        __syncthreads();
        {
            const h8* g = gB + (size_t)(mt >> 1) * 24 * 128 + (mt & 1) * 64;
            #pragma unroll
            for (int qq = 0; qq < 6; qq++) {
                int idx = qq*256 + t;
                int slot = idx >> 6, row = idx & 63;
                gl_lds16(g + slot*128 + row, sB + slot*64 + row);
            }
        }
        __syncthreads();
        #pragma unroll
        for (int i = 0; i < 4; i++)
            #pragma unroll
            for (int j = 0; j < 2; j++) acc[i][j] = (f4){0.f,0.f,0.f,0.f};

        #pragma unroll
        for (int ks = 0; ks < 3; ks++) {
            const int hs = ks*4 + quad;
            h8 ah[4], alo[4], bh[2], blo[2];
            #pragma unroll
            for (int i = 0; i < 4; i++) {
                int ml = wm*64 + i*16 + col;
                ah[i]  = sN[hs*128 + ml];
                alo[i] = sN[(12+hs)*128 + ml];
            }
            #pragma unroll
            for (int j = 0; j < 2; j++) {
                int r = wn*32 + j*16 + col;
                bh[j]  = sB[hs*64 + r];
                blo[j] = sB[(12+hs)*64 + r];
            }
            #pragma unroll
            for (int i = 0; i < 4; i++)
                #pragma unroll
                for (int j = 0; j < 2; j++) {
                    acc[i][j] = __builtin_amdgcn_mfma_f32_16x16x32_f16(ah[i],  bh[j],  acc[i][j], 0, 0, 0);
                    acc[i][j] = __builtin_amdgcn_mfma_f32_16x16x32_f16(ah[i],  blo[j], acc[i][j], 0, 0, 0);
                    acc[i][j] = __builtin_amdgcn_mfma_f32_16x16x32_f16(alo[i], bh[j],  acc[i][j], 0, 0, 0);
                }
        }
        // epilogue: fold into per-n class sums (global atomics; m sorted by class)
        {
            int mm[2]; float m2[2], mx_[2], my_[2], mz_[2]; int pc[2];
            #pragma unroll
            for (int j = 0; j < 2; j++) {
                mm[j] = mb + wn*32 + j*16 + col;
                m2[j] = midn2[mm[j]];
                mx_[j] = midc[mm[j]*3+0]; my_[j] = midc[mm[j]*3+1]; mz_[j] = midc[mm[j]*3+2];
                pc[j] = cls_s[mm[j]];
            }
            int seg0 = cls_s[mb + wn*32];
            int seg1 = cls_s[mb + wn*32 + 31];
            if (seg0 == seg1) {   // wave's 32 cols uniform class
                #pragma unroll
                for (int e = 0; e < 16; e++) {
                    float rs = 0.f;
                    #pragma unroll
                    for (int j = 0; j < 2; j++) {
                        float dot = acc[e>>2][j][e&3] * (1.0f/65536.0f);
                        float fd = fmaxf(nn2[e] + m2[j] - 2.0f*dot, 0.0f);
                        float dx = ncx[e]-mx_[j], dy = ncy[e]-my_[j], dz = ncz[e]-mz_[j];
                        float dc = dx*dx + dy*dy + dz*dz;
                        rs += __expf(-8.0f*dc - (0.5f/0.09f)*fd);
                    }
                    rs += __shfl_xor(rs, 1, 64);
                    rs += __shfl_xor(rs, 2, 64);
                    rs += __shfl_xor(rs, 4, 64);
                    rs += __shfl_xor(rs, 8, 64);
                    if (col == 0) {
                        int nl = wm*64 + (e>>2)*16 + quad*4 + (e&3);
                        atomicAdd(&uwacc[(size_t)(n0 + nl)*OUT + seg0], rs);
                    }
                }
            } else {              // boundary tile (rare): per-lane run-length
                #pragma unroll
                for (int e = 0; e < 16; e++) {
                    int nl = wm*64 + (e>>2)*16 + quad*4 + (e&3);
                    float cur = 0.f; int cc = -1;
                    #pragma unroll
                    for (int j = 0; j < 2; j++) {
                        float dot = acc[e>>2][j][e&3] * (1.0f/65536.0f);
                        float fd = fmaxf(nn2[e] + m2[j] - 2.0f*dot, 0.0f);
                        float dx = ncx[e]-mx_[j], dy = ncy[e]-my_[j], dz = ncz[e]-mz_[j];
                        float dc = dx*dx + dy*dy + dz*dz;
                        float w = __expf(-8.0f*dc - (0.5f/0.09f)*fd);
                        if (pc[j] != cc) {
                            if (cc >= 0) atomicAdd(&uwacc[(size_t)(n0 + nl)*OUT + cc], cur);
                            cc = pc[j]; cur = 0.f;
                        }
                        cur += w;
                    }
                    if (cc >= 0) atomicAdd(&uwacc[(size_t)(n0 + nl)*OUT + cc], cur);
                }
            }
        }
    }
}

__global__ void k_uw_final(const float* __restrict__ uwacc, const float* __restrict__ svp,
                           float* __restrict__ out_uw, float* __restrict__ out_spu) {
    int n = blockIdx.x * 256 + threadIdx.x;
    if (n >= N) return;
    float s[OUT]; float tot = 0.f;
    #pragma unroll
    for (int k = 0; k < OUT; k++) { s[k] = uwacc[(size_t)n*OUT + k]; tot += s[k]; }
    float rden = 1.0f / (tot + 1e-16f);
    float p[OUT]; float mx = -3.4e38f;
    #pragma unroll
    for (int k = 0; k < OUT; k++) { p[k] = svp[(size_t)n*OUT + k]; mx = fmaxf(mx, p[k]); }
    float es = 0.f;
    #pragma unroll
    for (int k = 0; k < OUT; k++) { p[k] = __expf(p[k] - mx); es += p[k]; }
    float res = 1.0f / es;
    #pragma unroll
    for (int k = 0; k < OUT; k++) {
        float uw = s[k] * rden;
        out_uw[(size_t)n*OUT + k] = uw;
        out_spu[(size_t)n*OUT + k] = 0.5f * (p[k] * res) + 0.5f * uw;
    }
}

// ---------------------------------------------------------------- scatter (lg rows, last-wins)
__global__ void k_scatter_pre(const int* __restrict__ smi, const int* __restrict__ gtcls,
                              const float* __restrict__ spu, float* __restrict__ vals,
                              int* __restrict__ pos, int* __restrict__ flags) {
    int i = blockIdx.x * 256 + threadIdx.x;
    if (i >= LG) return;
    int idx = smi[i];
    float v = spu[(size_t)idx*OUT + gtcls[i]];
    vals[i] = v;
    if (v > 0.1f) atomicOr(&flags[0], 1);
    atomicMax(&pos[idx], i);
}

__global__ void k_scatter_apply(const int* __restrict__ smi, const int* __restrict__ gtcls,
                                const float* __restrict__ vals, const int* __restrict__ pos,
                                const int* __restrict__ flags, float* __restrict__ spu) {
    int i = blockIdx.x * 256 + threadIdx.x;
    if (i >= LG) return;
    int idx = smi[i];
    if (pos[idx] != i) return;
    float v = vals[i];
    bool tmp = flags[0] ? (v > 0.1f) : (v > 0.0f);
    if (!tmp) return;
    int cls = gtcls[i];
    #pragma unroll
    for (int k = 0; k < OUT; k++) spu[(size_t)idx*OUT + k] = (k == cls) ? 1.0f : 0.0f;
}

// ---------------------------------------------------------------- trust / finalize
__global__ void k_trust_pre(const float* __restrict__ spu, float* __restrict__ maxv,
                            int* __restrict__ amax, int* __restrict__ flags) {
    int n = blockIdx.x * 256 + threadIdx.x;
    if (n >= N) return;
    float best = spu[(size_t)n*OUT]; int bi = 0;
    #pragma unroll
    for (int k = 1; k < OUT; k++) {
        float v = spu[(size_t)n*OUT + k];
        if (v > best) { best = v; bi = k; }
    }
    maxv[n] = best; amax[n] = bi;
    if (best >= 0.9f) atomicOr(&flags[1], 1);
}

__global__ void k_finalize(const float* __restrict__ mf, const float* __restrict__ ori,
                           const float* __restrict__ maxv, const int* __restrict__ amax,
                           const int* __restrict__ flags,
                           float* __restrict__ out_trust, float* __restrict__ out_mf,
                           float* __restrict__ out_ori, float* __restrict__ out_pre) {
    int n = blockIdx.x * 256 + threadIdx.x;
    if (n >= N) return;
    float mv = maxv[n];
    bool tr = flags[1] ? (mv >= 0.9f) : (mv >= 0.85f);
    float m = tr ? 1.f : 0.f;
    out_trust[n] = m;
    const float4* src = (const float4*)(mf + (size_t)n * C);
    float4* dst = (float4*)(out_mf + (size_t)n * C);
    #pragma unroll
    for (int c = 0; c < 24; c++) {
        float4 v = src[c];
        v.x *= m; v.y *= m; v.z *= m; v.w *= m;
        dst[c] = v;
    }
    out_ori[n*3]   = ori[n*3]   * m;
    out_ori[n*3+1] = ori[n*3+1] * m;
    out_ori[n*3+2] = ori[n*3+2] * m;
    int bi = amax[n];
    #pragma unroll
    for (int k = 0; k < OUT; k++) out_pre[(size_t)n*OUT + k] = (k == bi) ? m : 0.f;
}

// ---------------------------------------------------------------- launch
extern "C" void kernel_launch(void* const* d_in, const int* in_sizes, int n_in,
                              void* d_out, int out_size, void* d_ws, size_t ws_size,
                              hipStream_t stream) {
    (void)in_sizes; (void)n_in; (void)out_size; (void)ws_size;
    const float* ssf     = (const float*)d_in[0];
    const float* scoords = (const float*)d_in[1];
    const float* gt      = (const float*)d_in[2];
    const float* svp     = (const float*)d_in[3];
    const float* mf      = (const float*)d_in[4];
    const float* ori     = (const float*)d_in[5];
    const float* posses  = (const float*)d_in[6];
    const int*   ran     = (const int*)d_in[7];

    float* out = (float*)d_out;
    float* out_trust = out;
    float* out_mf    = out_trust + N;
    float* out_ori   = out_mf + (size_t)N*C;
    float* out_pre   = out_ori + (size_t)N*3;
    float* out_uw    = out_pre + (size_t)N*OUT;
    float* out_spu   = out_uw  + (size_t)N*OUT;
    float* out_smi   = out_spu + (size_t)N*OUT;

    char* ws = (char*)d_ws;
    float*     w_diff  = (float*)(ws + OFF_DIFF);
    float*     w_al    = (float*)(ws + OFF_AL);
    float*     w_nmf2  = (float*)(ws + OFF_NMF2);
    float*     w_updf  = (float*)(ws + OFF_UPDF);
    int*       w_gtc   = (int*)(ws + OFF_GTC);
    int*       w_smi   = (int*)(ws + OFF_SMI);
    int*       w_perm  = (int*)(ws + OFF_PERM);
    _Float16*  w_aP    = (_Float16*)(ws + OFF_AP);
    _Float16*  w_bQ    = (_Float16*)(ws + OFF_BQ);
    _Float16*  w_mfP   = (_Float16*)(ws + OFF_MFP);
    _Float16*  w_midQ  = (_Float16*)(ws + OFF_MIDQ);
    float*     w_midn2 = (float*)(ws + OFF_MIDN2);
    float*     w_midc  = (float*)(ws + OFF_MIDC);
    int*       w_cls   = (int*)(ws + OFF_CLS);
    float*     w_pav   = (float*)(ws + OFF_PAV);
    int*       w_pai   = (int*)(ws + OFF_PAI);
    float*     w_uwacc = (float*)(ws + OFF_UWACC);
    float*     w_vals  = (float*)(ws + OFF_VALS);
    int*       w_pos   = (int*)(ws + OFF_POS);
    float*     w_maxv  = (float*)(ws + OFF_MAXV);
    int*       w_amax  = (int*)(ws + OFF_AMAX);
    int*       w_flags = (int*)(ws + OFF_FLAGS);
    int*       w_cnt   = (int*)(ws + OFF_CNT);
    int*       w_meta  = (int*)(ws + OFF_META);

    hipMemsetAsync(w_pos, 0xFF, (size_t)N*4, stream);   // -1
    hipMemsetAsync(w_flags, 0, 8, stream);
    hipMemsetAsync(w_cnt, 0, OUT*4, stream);
    hipMemsetAsync(w_uwacc, 0, (size_t)N*OUT*4, stream);

    k_diff<<<1, 64, 0, stream>>>(posses, w_diff);
    k_prep_m<<<M/128, 256, 0, stream>>>(ssf, scoords, gt, ran, w_diff,
                                        w_al, w_aP, w_updf, w_gtc, w_cnt);
    k_prep_n<<<N/128, 256, 0, stream>>>(mf, w_bQ, w_mfP, w_nmf2);
    k_argmin<<<dim3(M/128, NSPA), 256, 0, stream>>>(w_aP, w_bQ, w_al, ori, w_pav, w_pai);
    k_argmin_reduce<<<M/256, 256, 0, stream>>>(w_pav, w_pai, w_smi, out_smi);
    k_scan<<<1, 64, 0, stream>>>(w_cnt, w_meta);
    k_permute<<<M/256, 256, 0, stream>>>(w_gtc, w_updf, w_meta, w_perm);
    k_gather_sorted<<<(M+128)/256, 256, 0, stream>>>(w_meta, w_perm, w_smi, w_gtc,
                                                     w_mfP, w_nmf2, ori,
                                                     w_midQ, w_midn2, w_midc, w_cls);
    k_uw<<<dim3(N/128, NSPB), 256, 0, stream>>>(w_mfP, w_midQ, w_nmf2, ori,
                                                w_midn2, w_midc, w_cls, w_meta, w_uwacc);
    k_uw_final<<<N/256, 256, 0, stream>>>(w_uwacc, svp, out_uw, out_spu);
    k_scatter_pre<<<LG/256, 256, 0, stream>>>(w_smi, w_gtc, out_spu, w_vals, w_pos, w_flags);
    k_scatter_apply<<<LG/256, 256, 0, stream>>>(w_smi, w_gtc, w_vals, w_pos, w_flags, out_spu);
    k_trust_pre<<<N/256, 256, 0, stream>>>(out_spu, w_maxv, w_amax, w_flags);
    k_finalize<<<N/256, 256, 0, stream>>>(mf, ori, w_maxv, w_amax, w_flags,
                                          out_trust, out_mf, out_ori, out_pre);
}

// Round 15
// 288.715 us; speedup vs baseline: 1.7654x; 1.7654x over previous
//
#include <hip/hip_runtime.h>
#include <math.h>

#define N 8192
#define M 8192
#define C 96
#define OUT 20
#define LG 2048

#define KP2 192     // stored K per row: [hi(96)|lo(96)] fp16, 24 h8 slots
#define NSPA 4      // y-slices pass A (256 blocks = 1/CU, 8 macro-tiles each)
#define NSPB 4      // y-slices pass B (256 blocks = 1/CU, ~5 macro-tiles each)

typedef _Float16 h8 __attribute__((ext_vector_type(8)));
typedef float    f4 __attribute__((ext_vector_type(4)));

// async global->LDS, 16B per lane, no VGPR round-trip (m97 path)
__device__ __forceinline__ void gl_lds16(const h8* g, h8* l) {
    __builtin_amdgcn_global_load_lds(
        (const __attribute__((address_space(1))) unsigned int*)g,
        (__attribute__((address_space(3))) unsigned int*)l,
        16, 0, 0);
}

// tile-slot-major h8 index: rows grouped in 128-row tiles, slot-major inside
__device__ __forceinline__ size_t tsm24(int row, int slot) {
    return ((size_t)(row >> 7) * 24 + slot) * 128 + (row & 127);
}

// ---------------- workspace layout (bytes, all 256-aligned) ----------------
constexpr size_t OFF_DIFF  = 0;
constexpr size_t OFF_AL    = 256;
constexpr size_t OFF_NMF2  = OFF_AL    + (size_t)M*3*4;
constexpr size_t OFF_UPDF  = OFF_NMF2  + (size_t)N*4;
constexpr size_t OFF_GTC   = OFF_UPDF  + (size_t)M*4;
constexpr size_t OFF_SMI   = OFF_GTC   + (size_t)M*4;
constexpr size_t OFF_PERM  = OFF_SMI   + (size_t)M*4;
constexpr size_t OFF_AP    = OFF_PERM  + (size_t)M*4;            // M x 192 fp16 (tsm24)
constexpr size_t OFF_BQ    = OFF_AP    + (size_t)M*KP2*2;        // N x 192 fp16
constexpr size_t OFF_MFP   = OFF_BQ    + (size_t)N*KP2*2;        // N x 192 fp16
constexpr size_t OFF_MIDQ  = OFF_MFP   + (size_t)N*KP2*2;        // (M+256) x 192 fp16
constexpr size_t OFF_MIDN2 = OFF_MIDQ  + (size_t)(M+256)*KP2*2;
constexpr size_t OFF_MIDC  = OFF_MIDN2 + (size_t)(M+256)*4;
constexpr size_t OFF_CLS   = OFF_MIDC  + (size_t)(M+256)*3*4;
constexpr size_t OFF_PAV   = OFF_CLS   + (size_t)(M+256)*4;      // NSPA x M
constexpr size_t OFF_PAI   = OFF_PAV   + (size_t)NSPA*M*4;
constexpr size_t OFF_PB    = OFF_PAI   + (size_t)NSPA*M*4;       // NSPB x N x 20
constexpr size_t OFF_VALS  = OFF_PB    + (size_t)NSPB*N*OUT*4;
constexpr size_t OFF_POS   = OFF_VALS  + (size_t)LG*4;
constexpr size_t OFF_MAXV  = OFF_POS   + (size_t)N*4;
constexpr size_t OFF_AMAX  = OFF_MAXV  + (size_t)N*4;
constexpr size_t OFF_FLAGS = OFF_AMAX  + (size_t)N*4;
constexpr size_t OFF_CNT   = OFF_FLAGS + 256;
constexpr size_t OFF_META  = OFF_CNT   + 256;   // [0]=Mact [1]=nmacro [2..21]=cursor

// ---------------------------------------------------------------- 4x4 inverse
__global__ void k_diff(const float* __restrict__ posses, float* __restrict__ diff) {
    if (threadIdx.x != 0 || blockIdx.x != 0) return;
    float a[4][8];
    for (int i = 0; i < 4; i++)
        for (int j = 0; j < 4; j++) {
            a[i][j]     = posses[16 + i*4 + j];
            a[i][4 + j] = (i == j) ? 1.f : 0.f;
        }
    for (int col = 0; col < 4; col++) {
        int piv = col; float mx = fabsf(a[col][col]);
        for (int r = col + 1; r < 4; r++) {
            float v = fabsf(a[r][col]);
            if (v > mx) { mx = v; piv = r; }
        }
        if (piv != col)
            for (int j = 0; j < 8; j++) { float t = a[col][j]; a[col][j] = a[piv][j]; a[piv][j] = t; }
        float inv = 1.0f / a[col][col];
        for (int j = 0; j < 8; j++) a[col][j] *= inv;
        for (int r = 0; r < 4; r++) {
            if (r == col) continue;
            float f = a[r][col];
            for (int j = 0; j < 8; j++) a[r][j] -= f * a[col][j];
        }
    }
    for (int i = 0; i < 4; i++)
        for (int j = 0; j < 4; j++) {
            float s = 0.f;
            for (int k = 0; k < 4; k++) s += a[i][4 + k] * posses[k*4 + j];
            diff[i*4 + j] = s;
        }
}

// ---------------------------------------------------------------- per-m prep (+ class hist)
__global__ void k_prep_m(const float* __restrict__ ssf, const float* __restrict__ scoords,
                         const float* __restrict__ gt, const int* __restrict__ ran_mask,
                         const float* __restrict__ diff,
                         float* __restrict__ al, _Float16* __restrict__ aP,
                         float* __restrict__ updf, int* __restrict__ gtcls,
                         int* __restrict__ cnt) {
    __shared__ int hcnt[OUT];
    const int tt = threadIdx.x;
    if (tt < OUT) hcnt[tt] = 0;
    __syncthreads();
    const int m = blockIdx.x * 128 + (tt >> 1);
    const int h = tt & 1;
    {
        const float4* r4 = (const float4*)(ssf + (size_t)m * C);
        float4 row[24]; float s = 0.f;
        #pragma unroll
        for (int c = 0; c < 24; c++) {
            float4 v = r4[c];
            row[c] = v;
            s += v.x*v.x + v.y*v.y + v.z*v.z + v.w*v.w;
        }
        float scale = 256.0f / sqrtf(s);
        h8* dst = (h8*)aP;
        #pragma unroll
        for (int qq = 0; qq < 6; qq++) {
            int q = h*6 + qq;
            float4 u = row[2*q], v = row[2*q+1];
            float xs[8] = {u.x,u.y,u.z,u.w,v.x,v.y,v.z,v.w};
            h8 hi, lo;
            #pragma unroll
            for (int e = 0; e < 8; e++) {
                float xv = xs[e] * scale;
                _Float16 hh = (_Float16)xv;
                hi[e] = hh;
                lo[e] = (_Float16)(xv - (float)hh);
            }
            dst[tsm24(m, q)]      = hi;
            dst[tsm24(m, 12 + q)] = lo;
        }
        if (h == 0) {
            float x = scoords[m*3], y = scoords[m*3+1], z = scoords[m*3+2];
            #pragma unroll
            for (int j = 0; j < 3; j++)
                al[m*3 + j] = diff[j*4+0]*x + diff[j*4+1]*y + diff[j*4+2]*z + diff[j*4+3];
            int best = 0; float bv = gt[(size_t)m*OUT];
            #pragma unroll
            for (int k = 1; k < OUT; k++) {
                float v = gt[(size_t)m*OUT + k];
                if (v > bv) { bv = v; best = k; }
            }
            gtcls[m] = best;
            bool upd = (best < 9 || m < LG || ran_mask[m] == 1);
            updf[m] = upd ? 1.f : 0.f;
            if (upd) atomicAdd(&hcnt[best], 1);
        }
    }
    __syncthreads();
    if (tt < OUT) atomicAdd(&cnt[tt], hcnt[tt]);
}

// ---------------------------------------------------------------- per-n prep (2 threads/row)
__global__ void k_prep_n(const float* __restrict__ mf, _Float16* __restrict__ bQ,
                         _Float16* __restrict__ mfP, float* __restrict__ nmf2) {
    const int tt = threadIdx.x;
    const int n = blockIdx.x * 128 + (tt >> 1);
    const int h = tt & 1;
    const float4* r4 = (const float4*)(mf + (size_t)n * C);
    float4 row[24]; float s = 0.f;
    #pragma unroll
    for (int c = 0; c < 24; c++) {
        float4 v = r4[c];
        row[c] = v;
        s += v.x*v.x + v.y*v.y + v.z*v.z + v.w*v.w;
    }
    if (h == 0) nmf2[n] = s;
    float scn = 256.0f / sqrtf(s);
    h8* dB = (h8*)bQ;
    h8* dF = (h8*)mfP;
    #pragma unroll
    for (int qq = 0; qq < 6; qq++) {
        int q = h*6 + qq;
        float4 u = row[2*q], v = row[2*q+1];
        float xs[8] = {u.x,u.y,u.z,u.w,v.x,v.y,v.z,v.w};
        h8 hiN, loN, hiF, loF;
        #pragma unroll
        for (int e = 0; e < 8; e++) {
            float xn = xs[e] * scn;
            _Float16 hn = (_Float16)xn;
            hiN[e] = hn; loN[e] = (_Float16)(xn - (float)hn);
            float xf = xs[e] * 256.0f;
            _Float16 hf = (_Float16)xf;
            hiF[e] = hf; loF[e] = (_Float16)(xf - (float)hf);
        }
        dB[tsm24(n, q)]    = hiN;
        dB[tsm24(n, 12+q)] = loN;
        dF[tsm24(n, q)]    = hiF;
        dF[tsm24(n, 12+q)] = loF;
    }
}

// ---------------------------------------------------------------- pass A: MFMA argmin
// Block: 128m resident full-K (hi+lo) in LDS; streams 8 macro-tiles of 256n via
// global_load_lds. 256 blocks = 1/CU, single scheduling round.
__global__ __launch_bounds__(512, 1) void k_argmin(
        const _Float16* __restrict__ aP, const _Float16* __restrict__ bQ,
        const float* __restrict__ al, const float* __restrict__ ori,
        float* __restrict__ pav, int* __restrict__ pai) {
    __shared__ h8 sA[24*128];          // 48 KB
    __shared__ h8 sB[2*24*128];        // 96 KB (256 rows = 2 row-tiles)
    __shared__ float xv[4*128];
    __shared__ int   xi[4*128];
    const int t = threadIdx.x;
    const int wave = t >> 6, lane = t & 63;
    const int col = lane & 15, quad = lane >> 4;
    const int wm = wave >> 2, wn = wave & 3;
    const int m0 = blockIdx.x * 128;
    const int sp = blockIdx.y;

    {   // stage resident A async (flat: global tile layout == LDS layout)
        const h8* gA = (const h8*)aP + (size_t)blockIdx.x * 24 * 128;
        #pragma unroll
        for (int q = 0; q < 6; q++) gl_lds16(gA + q*512 + t, sA + q*512 + t);
    }
    float mcx[16], mcy[16], mcz[16];
    #pragma unroll
    for (int e = 0; e < 16; e++) {
        int ml = wm*64 + (e>>2)*16 + quad*4 + (e&3);
        mcx[e] = al[(m0+ml)*3+0]; mcy[e] = al[(m0+ml)*3+1]; mcz[e] = al[(m0+ml)*3+2];
    }
    float best[16]; int bidx[16];
    #pragma unroll
    for (int e = 0; e < 16; e++) { best[e] = 3.4e38f; bidx[e] = 0; }

    const h8* gB = (const h8*)bQ;
    f4 acc[4][4];
    for (int u = 0; u < 32/NSPA; u++) {
        const int tile = sp + u*NSPA;
        __syncthreads();                       // prev compute done reading sB
        {
            const h8* g = gB + (size_t)(2*tile) * 24 * 128;
            #pragma unroll
            for (int q = 0; q < 12; q++) gl_lds16(g + q*512 + t, sB + q*512 + t);
        }
        __syncthreads();                       // drains vmcnt -> sA/sB visible
        #pragma unroll
        for (int i = 0; i < 4; i++)
            #pragma unroll
            for (int j = 0; j < 4; j++) acc[i][j] = (f4){0.f,0.f,0.f,0.f};

        #pragma unroll
        for (int ks = 0; ks < 3; ks++) {
            const int hs = ks*4 + quad;        // hi slot; lo slot = 12+hs
            h8 ah[4], alo[4], bh[4], blo[4];
            #pragma unroll
            for (int i = 0; i < 4; i++) {
                int ml = wm*64 + i*16 + col;
                ah[i]  = sA[hs*128 + ml];
                alo[i] = sA[(12+hs)*128 + ml];
            }
            #pragma unroll
            for (int j = 0; j < 4; j++) {
                int r = wn*64 + j*16 + col;
                int tb = (r >> 7) * 3072, rl = r & 127;
                bh[j]  = sB[tb + hs*128 + rl];
                blo[j] = sB[tb + (12+hs)*128 + rl];
            }
            #pragma unroll
            for (int i = 0; i < 4; i++)
                #pragma unroll
                for (int j = 0; j < 4; j++) {
                    acc[i][j] = __builtin_amdgcn_mfma_f32_16x16x32_f16(ah[i],  bh[j],  acc[i][j], 0, 0, 0);
                    acc[i][j] = __builtin_amdgcn_mfma_f32_16x16x32_f16(ah[i],  blo[j], acc[i][j], 0, 0, 0);
                    acc[i][j] = __builtin_amdgcn_mfma_f32_16x16x32_f16(alo[i], bh[j],  acc[i][j], 0, 0, 0);
                }
        }
        // epilogue: running per-lane argmin over this macro-tile
        const int n0t = tile * 256;
        #pragma unroll
        for (int j = 0; j < 4; j++) {
            int n = n0t + wn*64 + j*16 + col;
            float ncx = ori[n*3+0], ncy = ori[n*3+1], ncz = ori[n*3+2];
            #pragma unroll
            for (int e = 0; e < 16; e++) {
                float dot = acc[e>>2][j][e&3] * (1.0f/65536.0f);
                float dx = mcx[e]-ncx, dy = mcy[e]-ncy, dz = mcz[e]-ncz;
                float d2 = dx*dx + dy*dy + dz*dz;
                float sim = 2.0f - dot - __expf(-2.0f*d2);
                if (sim < best[e]) { best[e] = sim; bidx[e] = n; }
            }
        }
    }
    // butterfly over 16 col-lanes, once per block
    #pragma unroll
    for (int e = 0; e < 16; e++) {
        float bv = best[e]; int bi = bidx[e];
        #pragma unroll
        for (int d = 1; d < 16; d <<= 1) {
            float ov = __shfl_xor(bv, d, 64);
            int   oi = __shfl_xor(bi, d, 64);
            if (ov < bv || (ov == bv && oi < bi)) { bv = ov; bi = oi; }
        }
        best[e] = bv; bidx[e] = bi;
    }
    if (col == 0) {
        #pragma unroll
        for (int e = 0; e < 16; e++) {
            int ml = wm*64 + (e>>2)*16 + quad*4 + (e&3);
            xv[wn*128 + ml] = best[e];
            xi[wn*128 + ml] = bidx[e];
        }
    }
    __syncthreads();
    if (t < 128) {   // single writer per (sp, m)
        float bv = xv[t]; int bi = xi[t];
        #pragma unroll
        for (int w = 1; w < 4; w++) {
            float v = xv[w*128 + t]; int i2 = xi[w*128 + t];
            if (v < bv || (v == bv && i2 < bi)) { bv = v; bi = i2; }
        }
        pav[(size_t)sp * M + m0 + t] = bv;
        pai[(size_t)sp * M + m0 + t] = bi;
    }
}

__global__ void k_argmin_reduce(const float* __restrict__ pav, const int* __restrict__ pai,
                                int* __restrict__ smi, float* __restrict__ out_smi) {
    int m = blockIdx.x * 256 + threadIdx.x;
    if (m >= M) return;
    float best = 3.4e38f; int bidx = 0;
    for (int sp = 0; sp < NSPA; sp++) {
        float v = pav[(size_t)sp * M + m];
        int   i = pai[(size_t)sp * M + m];
        if (v < best || (v == best && i < bidx)) { best = v; bidx = i; }
    }
    smi[m] = bidx;
    out_smi[m] = (float)bidx;
}

// ---------------------------------------------------------------- scan + permute (counting sort)
__global__ void k_scan(const int* __restrict__ cnt, int* __restrict__ meta) {
    if (threadIdx.x != 0 || blockIdx.x != 0) return;
    int run = 0;
    for (int k = 0; k < OUT; k++) { meta[2 + k] = run; run += cnt[k]; }
    meta[0] = run;
    meta[1] = (run + 255) / 256;      // macro-tiles of 256
}

__global__ void k_permute(const int* __restrict__ gtcls, const float* __restrict__ updf,
                          int* __restrict__ meta, int* __restrict__ perm) {
    int m = blockIdx.x * 256 + threadIdx.x;
    if (m >= M) return;
    if (updf[m] == 0.f) return;
    int pos = atomicAdd(&meta[2 + gtcls[m]], 1);
    perm[pos] = m;
}

// gather sorted+compacted mid rows (straight 24-slot copy), pad to 256 boundary
__global__ void k_gather_sorted(const int* __restrict__ meta, const int* __restrict__ perm,
                                const int* __restrict__ smi, const int* __restrict__ gtcls,
                                const _Float16* __restrict__ mfP, const float* __restrict__ nmf2,
                                const float* __restrict__ ori,
                                _Float16* __restrict__ midQ, float* __restrict__ midn2,
                                float* __restrict__ midc, int* __restrict__ cls_s) {
    int rr = blockIdx.x * 256 + threadIdx.x;
    int mact = meta[0];
    int mpad = meta[1] * 256;
    const h8* src = (const h8*)mfP;
    h8* dst = (h8*)midQ;
    if (rr < mact) {
        int m = perm[rr];
        int s = smi[m];
        #pragma unroll
        for (int q = 0; q < 24; q++) dst[tsm24(rr, q)] = src[tsm24(s, q)];
        midn2[rr] = nmf2[s];
        midc[rr*3+0] = ori[s*3+0];
        midc[rr*3+1] = ori[s*3+1];
        midc[rr*3+2] = ori[s*3+2];
        cls_s[rr] = gtcls[m];
    } else if (rr < mpad) {
        h8 z = (h8)(_Float16)0.f;
        #pragma unroll
        for (int q = 0; q < 24; q++) dst[tsm24(rr, q)] = z;
        midn2[rr] = 1e9f;     // w = exp(-5.55e9) == 0 exactly
        midc[rr*3+0] = 0.f; midc[rr*3+1] = 0.f; midc[rr*3+2] = 0.f;
        cls_s[rr] = 0;
    }
}

// ---------------------------------------------------------------- pass B: MFMA class-binned sums
__global__ __launch_bounds__(512, 1) void k_uw(
        const _Float16* __restrict__ mfP, const _Float16* __restrict__ midQ,
        const float* __restrict__ nmf2, const float* __restrict__ ori,
        const float* __restrict__ midn2, const float* __restrict__ midc,
        const int* __restrict__ cls_s, const int* __restrict__ meta,
        float* __restrict__ pb) {
    __shared__ h8 sN[24*128];          // 48 KB resident n-rows
    __shared__ h8 sB[2*24*128];        // 96 KB streamed mid macro-tile
    __shared__ float bins[128*21];
    const int t = threadIdx.x;
    const int wave = t >> 6, lane = t & 63;
    const int col = lane & 15, quad = lane >> 4;
    const int wm = wave >> 2, wn = wave & 3;
    const int n0 = blockIdx.x * 128;
    const int sp = blockIdx.y;
    const int nmac = meta[1];

    {   // stage resident n-rows async
        const h8* gN = (const h8*)mfP + (size_t)blockIdx.x * 24 * 128;
        #pragma unroll
        for (int q = 0; q < 6; q++) gl_lds16(gN + q*512 + t, sN + q*512 + t);
    }
    for (int i = t; i < 128*21; i += 512) bins[i] = 0.f;

    float nn2[16], ncx[16], ncy[16], ncz[16];
    #pragma unroll
    for (int e = 0; e < 16; e++) {
        int nl = wm*64 + (e>>2)*16 + quad*4 + (e&3);
        int n = n0 + nl;
        nn2[e] = nmf2[n];
        ncx[e] = ori[n*3+0]; ncy[e] = ori[n*3+1]; ncz[e] = ori[n*3+2];
    }

    const h8* gB = (const h8*)midQ;
    f4 acc[4][4];
    for (int mt = sp; mt < nmac; mt += NSPB) {
        const int mb = mt * 256;
        __syncthreads();
        {
            const h8* g = gB + (size_t)(2*mt) * 24 * 128;
            #pragma unroll
            for (int q = 0; q < 12; q++) gl_lds16(g + q*512 + t, sB + q*512 + t);
        }
        __syncthreads();
        #pragma unroll
        for (int i = 0; i < 4; i++)
            #pragma unroll
            for (int j = 0; j < 4; j++) acc[i][j] = (f4){0.f,0.f,0.f,0.f};

        #pragma unroll
        for (int ks = 0; ks < 3; ks++) {
            const int hs = ks*4 + quad;
            h8 ah[4], alo[4], bh[4], blo[4];
            #pragma unroll
            for (int i = 0; i < 4; i++) {
                int ml = wm*64 + i*16 + col;
                ah[i]  = sN[hs*128 + ml];
                alo[i] = sN[(12+hs)*128 + ml];
            }
            #pragma unroll
            for (int j = 0; j < 4; j++) {
                int r = wn*64 + j*16 + col;
                int tb = (r >> 7) * 3072, rl = r & 127;
                bh[j]  = sB[tb + hs*128 + rl];
                blo[j] = sB[tb + (12+hs)*128 + rl];
            }
            #pragma unroll
            for (int i = 0; i < 4; i++)
                #pragma unroll
                for (int j = 0; j < 4; j++) {
                    acc[i][j] = __builtin_amdgcn_mfma_f32_16x16x32_f16(ah[i],  bh[j],  acc[i][j], 0, 0, 0);
                    acc[i][j] = __builtin_amdgcn_mfma_f32_16x16x32_f16(ah[i],  blo[j], acc[i][j], 0, 0, 0);
                    acc[i][j] = __builtin_amdgcn_mfma_f32_16x16x32_f16(alo[i], bh[j],  acc[i][j], 0, 0, 0);
                }
        }
        // epilogue: fold into class bins (LDS)
        {
            int mm[4]; float m2[4], mx_[4], my_[4], mz_[4]; int pc[4];
            #pragma unroll
            for (int j = 0; j < 4; j++) {
                mm[j] = mb + wn*64 + j*16 + col;
                m2[j] = midn2[mm[j]];
                mx_[j] = midc[mm[j]*3+0]; my_[j] = midc[mm[j]*3+1]; mz_[j] = midc[mm[j]*3+2];
                pc[j] = cls_s[mm[j]];
            }
            int seg0 = cls_s[mb + wn*64];
            int seg1 = cls_s[mb + wn*64 + 63];
            if (seg0 == seg1) {   // wave's 64 cols uniform class
                #pragma unroll
                for (int e = 0; e < 16; e++) {
                    float rs = 0.f;
                    #pragma unroll
                    for (int j = 0; j < 4; j++) {
                        float dot = acc[e>>2][j][e&3] * (1.0f/65536.0f);
                        float fd = fmaxf(nn2[e] + m2[j] - 2.0f*dot, 0.0f);
                        float dx = ncx[e]-mx_[j], dy = ncy[e]-my_[j], dz = ncz[e]-mz_[j];
                        float dc = dx*dx + dy*dy + dz*dz;
                        rs += __expf(-8.0f*dc - (0.5f/0.09f)*fd);
                    }
                    rs += __shfl_xor(rs, 1, 64);
                    rs += __shfl_xor(rs, 2, 64);
                    rs += __shfl_xor(rs, 4, 64);
                    rs += __shfl_xor(rs, 8, 64);
                    if (col == 0) {
                        int nl = wm*64 + (e>>2)*16 + quad*4 + (e&3);
                        atomicAdd(&bins[nl*21 + seg0], rs);
                    }
                }
            } else {              // boundary segment: per-lane run-length into LDS
                #pragma unroll
                for (int e = 0; e < 16; e++) {
                    int nl = wm*64 + (e>>2)*16 + quad*4 + (e&3);
                    float cur = 0.f; int cc = -1;
                    #pragma unroll
                    for (int j = 0; j < 4; j++) {
                        float dot = acc[e>>2][j][e&3] * (1.0f/65536.0f);
                        float fd = fmaxf(nn2[e] + m2[j] - 2.0f*dot, 0.0f);
                        float dx = ncx[e]-mx_[j], dy = ncy[e]-my_[j], dz = ncz[e]-mz_[j];
                        float dc = dx*dx + dy*dy + dz*dz;
                        float w = __expf(-8.0f*dc - (0.5f/0.09f)*fd);
                        if (pc[j] != cc) {
                            if (cc >= 0) atomicAdd(&bins[nl*21 + cc], cur);
                            cc = pc[j]; cur = 0.f;
                        }
                        cur += w;
                    }
                    if (cc >= 0) atomicAdd(&bins[nl*21 + cc], cur);
                }
            }
        }
    }
    __syncthreads();
    for (int i = t; i < 128*OUT; i += 512) {
        int loc = i / OUT, k = i - loc*OUT;
        pb[((size_t)sp*N + n0 + loc)*OUT + k] = bins[loc*21 + k];
    }
}

__global__ void k_uw_final(const float* __restrict__ pb, const float* __restrict__ svp,
                           float* __restrict__ out_uw, float* __restrict__ out_spu) {
    int n = blockIdx.x * 256 + threadIdx.x;
    if (n >= N) return;
    float s[OUT];
    #pragma unroll
    for (int k = 0; k < OUT; k++) s[k] = 0.f;
    for (int sp = 0; sp < NSPB; sp++) {
        size_t base = ((size_t)sp * N + n) * OUT;
        #pragma unroll
        for (int k = 0; k < OUT; k++) s[k] += pb[base + k];
    }
    float tot = 0.f;
    #pragma unroll
    for (int k = 0; k < OUT; k++) tot += s[k];
    float rden = 1.0f / (tot + 1e-16f);
    float p[OUT]; float mx = -3.4e38f;
    #pragma unroll
    for (int k = 0; k < OUT; k++) { p[k] = svp[(size_t)n*OUT + k]; mx = fmaxf(mx, p[k]); }
    float es = 0.f;
    #pragma unroll
    for (int k = 0; k < OUT; k++) { p[k] = __expf(p[k] - mx); es += p[k]; }
    float res = 1.0f / es;
    #pragma unroll
    for (int k = 0; k < OUT; k++) {
        float uw = s[k] * rden;
        out_uw[(size_t)n*OUT + k] = uw;
        out_spu[(size_t)n*OUT + k] = 0.5f * (p[k] * res) + 0.5f * uw;
    }
}

// ---------------------------------------------------------------- scatter (lg rows, last-wins)
__global__ void k_scatter_pre(const int* __restrict__ smi, const int* __restrict__ gtcls,
                              const float* __restrict__ spu, float* __restrict__ vals,
                              int* __restrict__ pos, int* __restrict__ flags) {
    int i = blockIdx.x * 256 + threadIdx.x;
    if (i >= LG) return;
    int idx = smi[i];
    float v = spu[(size_t)idx*OUT + gtcls[i]];
    vals[i] = v;
    if (v > 0.1f) atomicOr(&flags[0], 1);
    atomicMax(&pos[idx], i);
}

__global__ void k_scatter_apply(const int* __restrict__ smi, const int* __restrict__ gtcls,
                                const float* __restrict__ vals, const int* __restrict__ pos,
                                const int* __restrict__ flags, float* __restrict__ spu) {
    int i = blockIdx.x * 256 + threadIdx.x;
    if (i >= LG) return;
    int idx = smi[i];
    if (pos[idx] != i) return;
    float v = vals[i];
    bool tmp = flags[0] ? (v > 0.1f) : (v > 0.0f);
    if (!tmp) return;
    int cls = gtcls[i];
    #pragma unroll
    for (int k = 0; k < OUT; k++) spu[(size_t)idx*OUT + k] = (k == cls) ? 1.0f : 0.0f;
}

// ---------------------------------------------------------------- trust / finalize
__global__ void k_trust_pre(const float* __restrict__ spu, float* __restrict__ maxv,
                            int* __restrict__ amax, int* __restrict__ flags) {
    int n = blockIdx.x * 256 + threadIdx.x;
    if (n >= N) return;
    float best = spu[(size_t)n*OUT]; int bi = 0;
    #pragma unroll
    for (int k = 1; k < OUT; k++) {
        float v = spu[(size_t)n*OUT + k];
        if (v > best) { best = v; bi = k; }
    }
    maxv[n] = best; amax[n] = bi;
    if (best >= 0.9f) atomicOr(&flags[1], 1);
}

__global__ void k_finalize(const float* __restrict__ mf, const float* __restrict__ ori,
                           const float* __restrict__ maxv, const int* __restrict__ amax,
                           const int* __restrict__ flags,
                           float* __restrict__ out_trust, float* __restrict__ out_mf,
                           float* __restrict__ out_ori, float* __restrict__ out_pre) {
    int n = blockIdx.x * 256 + threadIdx.x;
    if (n >= N) return;
    float mv = maxv[n];
    bool tr = flags[1] ? (mv >= 0.9f) : (mv >= 0.85f);
    float m = tr ? 1.f : 0.f;
    out_trust[n] = m;
    const float4* src = (const float4*)(mf + (size_t)n * C);
    float4* dst = (float4*)(out_mf + (size_t)n * C);
    #pragma unroll
    for (int c = 0; c < 24; c++) {
        float4 v = src[c];
        v.x *= m; v.y *= m; v.z *= m; v.w *= m;
        dst[c] = v;
    }
    out_ori[n*3]   = ori[n*3]   * m;
    out_ori[n*3+1] = ori[n*3+1] * m;
    out_ori[n*3+2] = ori[n*3+2] * m;
    int bi = amax[n];
    #pragma unroll
    for (int k = 0; k < OUT; k++) out_pre[(size_t)n*OUT + k] = (k == bi) ? m : 0.f;
}

// ---------------------------------------------------------------- launch
extern "C" void kernel_launch(void* const* d_in, const int* in_sizes, int n_in,
                              void* d_out, int out_size, void* d_ws, size_t ws_size,
                              hipStream_t stream) {
    (void)in_sizes; (void)n_in; (void)out_size; (void)ws_size;
    const float* ssf     = (const float*)d_in[0];
    const float* scoords = (const float*)d_in[1];
    const float* gt      = (const float*)d_in[2];
    const float* svp     = (const float*)d_in[3];
    const float* mf      = (const float*)d_in[4];
    const float* ori     = (const float*)d_in[5];
    const float* posses  = (const float*)d_in[6];
    const int*   ran     = (const int*)d_in[7];

    float* out = (float*)d_out;
    float* out_trust = out;
    float* out_mf    = out_trust + N;
    float* out_ori   = out_mf + (size_t)N*C;
    float* out_pre   = out_ori + (size_t)N*3;
    float* out_uw    = out_pre + (size_t)N*OUT;
    float* out_spu   = out_uw  + (size_t)N*OUT;
    float* out_smi   = out_spu + (size_t)N*OUT;

    char* ws = (char*)d_ws;
    float*     w_diff  = (float*)(ws + OFF_DIFF);
    float*     w_al    = (float*)(ws + OFF_AL);
    float*     w_nmf2  = (float*)(ws + OFF_NMF2);
    float*     w_updf  = (float*)(ws + OFF_UPDF);
    int*       w_gtc   = (int*)(ws + OFF_GTC);
    int*       w_smi   = (int*)(ws + OFF_SMI);
    int*       w_perm  = (int*)(ws + OFF_PERM);
    _Float16*  w_aP    = (_Float16*)(ws + OFF_AP);
    _Float16*  w_bQ    = (_Float16*)(ws + OFF_BQ);
    _Float16*  w_mfP   = (_Float16*)(ws + OFF_MFP);
    _Float16*  w_midQ  = (_Float16*)(ws + OFF_MIDQ);
    float*     w_midn2 = (float*)(ws + OFF_MIDN2);
    float*     w_midc  = (float*)(ws + OFF_MIDC);
    int*       w_cls   = (int*)(ws + OFF_CLS);
    float*     w_pav   = (float*)(ws + OFF_PAV);
    int*       w_pai   = (int*)(ws + OFF_PAI);
    float*     w_pb    = (float*)(ws + OFF_PB);
    float*     w_vals  = (float*)(ws + OFF_VALS);
    int*       w_pos   = (int*)(ws + OFF_POS);
    float*     w_maxv  = (float*)(ws + OFF_MAXV);
    int*       w_amax  = (int*)(ws + OFF_AMAX);
    int*       w_flags = (int*)(ws + OFF_FLAGS);
    int*       w_cnt   = (int*)(ws + OFF_CNT);
    int*       w_meta  = (int*)(ws + OFF_META);

    hipMemsetAsync(w_pos, 0xFF, (size_t)N*4, stream);   // -1
    hipMemsetAsync(w_flags, 0, 8, stream);
    hipMemsetAsync(w_cnt, 0, OUT*4, stream);

    k_diff<<<1, 64, 0, stream>>>(posses, w_diff);
    k_prep_m<<<M/128, 256, 0, stream>>>(ssf, scoords, gt, ran, w_diff,
                                        w_al, w_aP, w_updf, w_gtc, w_cnt);
    k_prep_n<<<N/128, 256, 0, stream>>>(mf, w_bQ, w_mfP, w_nmf2);
    k_argmin<<<dim3(M/128, NSPA), 512, 0, stream>>>(w_aP, w_bQ, w_al, ori, w_pav, w_pai);
    k_argmin_reduce<<<M/256, 256, 0, stream>>>(w_pav, w_pai, w_smi, out_smi);
    k_scan<<<1, 64, 0, stream>>>(w_cnt, w_meta);
    k_permute<<<M/256, 256, 0, stream>>>(w_gtc, w_updf, w_meta, w_perm);
    k_gather_sorted<<<(M+256)/256, 256, 0, stream>>>(w_meta, w_perm, w_smi, w_gtc,
                                                     w_mfP, w_nmf2, ori,
                                                     w_midQ, w_midn2, w_midc, w_cls);
    k_uw<<<dim3(N/128, NSPB), 512, 0, stream>>>(w_mfP, w_midQ, w_nmf2, ori,
                                                w_midn2, w_midc, w_cls, w_meta, w_pb);
    k_uw_final<<<N/256, 256, 0, stream>>>(w_pb, svp, out_uw, out_spu);
    k_scatter_pre<<<LG/256, 256, 0, stream>>>(w_smi, w_gtc, out_spu, w_vals, w_pos, w_flags);
    k_scatter_apply<<<LG/256, 256, 0, stream>>>(w_smi, w_gtc, w_vals, w_pos, w_flags, out_spu);
    k_trust_pre<<<N/256, 256, 0, stream>>>(out_spu, w_maxv, w_amax, w_flags);
    k_finalize<<<N/256, 256, 0, stream>>>(mf, ori, w_maxv, w_amax, w_flags,
                                          out_trust, out_mf, out_ori, out_pre);
}